// Round 7
// baseline (176.621 us; speedup 1.0000x reference)
//
#include <hip/hip_runtime.h>
#include <math.h>

#define NPTS 131072
#define KCOMP 256
#define DIM 32
#define NREAL 560                 // 528 tight-packed quad + 32 linear
#define NCH 18                    // 32-feature chunks: 17 full + 1 half (16)
#define PSIF_BYTES 294912         // 18 chunks * 1024 granules * 16 B
#define WS_NEED (PSIF_BYTES + KCOMP * 4)

typedef __attribute__((ext_vector_type(8))) short short8;
typedef __attribute__((ext_vector_type(16))) float f32x16;

__device__ __forceinline__ unsigned short f2bf(float v) {
    unsigned u = __float_as_uint(v);
    u += 0x7fffu + ((u >> 16) & 1u);   // RNE
    return (unsigned short)(u >> 16);
}

// pack two f32 -> two bf16 (lo | hi<<16). RTN (+0x8000) + byte-perm: 3 ops.
__device__ __forceinline__ unsigned pkbf(float lo, float hi) {
#if __has_builtin(__builtin_amdgcn_perm)
    const unsigned a = __float_as_uint(hi) + 0x8000u;
    const unsigned b = __float_as_uint(lo) + 0x8000u;
    return __builtin_amdgcn_perm(a, b, 0x07060302u);
#else
    return (unsigned)f2bf(lo) | ((unsigned)f2bf(hi) << 16);
#endif
}

// async global->LDS DMA, 16 B/lane; LDS dest = wave-uniform base + lane*16.
__device__ __forceinline__ void dma16(const uint4* g, uint4* s) {
    __builtin_amdgcn_global_load_lds(
        (const __attribute__((address_space(1))) void*)g,
        (__attribute__((address_space(3))) void*)s, 16, 0, 0);
}

// ---- compile-time feature decode: TIGHT triangular packing ----------------
// p in [0,528): (d,f) pairs, f>=d, row-major (row d has 32-d entries).
// p in [528,560): linear features (index p-528).
constexpr int PfxT(int d) { return 32 * d - (d * (d - 1)) / 2; }
constexpr int rowT(int p) { int d = 0; while (d < 31 && PfxT(d + 1) <= p) ++d; return d; }
constexpr int colT(int p) { return rowT(p) + (p - PfxT(rowT(p))); }

template<int P, int J>
__device__ __forceinline__ float genOne(const float (&x)[DIM]) {
    constexpr int p = P + J;
    if constexpr (p >= NREAL) {
        return 0.f;
    } else if constexpr (p >= 528) {
        return x[p - 528];
    } else {
        constexpr int d = rowT(p);
        constexpr int f = colT(p);
        static_assert(d >= 0 && d < 32 && f >= d && f < 32, "bad feature map");
        return x[d] * x[f];
    }
}

// ---------------------------------------------------------------------------
// Precompute: Psi column k scattered into frag-ordered PsiF (bf16), kc2 fp32.
// ---------------------------------------------------------------------------
__global__ __launch_bounds__(256) void gmm_pre(
    const float* __restrict__ S,
    const float* __restrict__ centers,
    const float* __restrict__ weights,
    unsigned short* __restrict__ PsiF,
    float* __restrict__ kc2)
{
    __shared__ float Sl[DIM][DIM + 1];
    __shared__ float As[DIM][DIM + 1];
    __shared__ float cl[DIM], ml[DIM];
    __shared__ float red[256];

    const int k = blockIdx.x, tid = threadIdx.x;

    for (int idx = tid; idx < DIM * DIM; idx += 256)
        Sl[idx >> 5][idx & 31] = S[(size_t)k * DIM * DIM + idx];
    if (tid < DIM) cl[tid] = centers[k * DIM + tid];
    __syncthreads();

    // A = S S^T
    for (int idx = tid; idx < DIM * DIM; idx += 256) {
        const int d = idx >> 5, f = idx & 31;
        float a = 0.f;
#pragma unroll
        for (int e = 0; e < DIM; ++e) a = fmaf(Sl[d][e], Sl[f][e], a);
        As[d][f] = a;
    }
    __syncthreads();

    if (tid < DIM) {
        float mv = 0.f;
#pragma unroll
        for (int f = 0; f < DIM; ++f) mv = fmaf(As[tid][f], cl[f], mv);
        ml[tid] = mv;
    }
    __syncthreads();

    // scatter Psi column k into frag positions (reads As diag+upper, ml).
    for (int p = tid; p < NREAL; p += 256) {
        float val;
        if (p < 528) {
            int d = 0, pr = 0;
            while (pr + (32 - d) <= p) { pr += (32 - d); ++d; }
            const int f = d + (p - pr);
            val = (f == d) ? -0.5f * As[d][d] : -As[d][f];
        } else {
            val = ml[p - 528];
        }
        const int c = p >> 6, kk = p & 63;
        const int s = kk >> 4, qq = (kk >> 3) & 1, j = kk & 7;
        const int ct = k >> 5, ll = qq * 32 + (k & 31);
        const int g = c * 2048 + (s * 8 + ct) * 64 + ll;
        PsiF[(size_t)g * 8 + j] = f2bf(val);
    }

    red[tid] = fabsf(weights[tid]);          // K == 256 == blockDim
    __syncthreads();                          // also fences As/ml reads above
    for (int off = 128; off > 0; off >>= 1) {
        if (tid < off) red[tid] += red[tid + off];
        __syncthreads();
    }
    const float wsum = red[0];

    // SPD Gaussian elimination: 1 barrier/step, logdet(A) = sum log(pivot_j).
    for (int j = 0; j < DIM - 1; ++j) {
        const float inv = 1.0f / As[j][j];
        for (int idx = tid; idx < DIM * DIM; idx += 256) {
            const int r = idx >> 5, c = idx & 31;
            if (r > j && c > j)
                As[r][c] = fmaf(-As[r][j] * inv, As[j][c], As[r][c]);
        }
        __syncthreads();
    }

    if (tid < DIM) red[tid] = __logf(As[tid][tid]);   // pivots > 0 (SPD)
    __syncthreads();
    if (tid == 0) {
        float sl = 0.f;
        for (int j = 0; j < DIM; ++j) sl += red[j];
        float cac = 0.f;
        for (int d2 = 0; d2 < DIM; ++d2) cac = fmaf(ml[d2], cl[d2], cac);
        kc2[k] = __logf(fabsf(weights[k])) - __logf(wsum + 1e-30f)
               + 0.5f * sl - 0.5f * cac;
    }
}

// ---------------------------------------------------------------------------
// Main MFMA kernel v8: SMALL blocks for occupancy + barrier stagger.
// 64 rows x 256 cols per block (2048 blocks), 512 threads (8 waves),
// wave tile 32r x 64c -> acc = 2 x f32x16 = 32 AGPR. LDS = sA 2x4 KB +
// sB 2x16 KB = 40 KB. __launch_bounds__(512,6) targets 3 blocks = 24
// waves/CU so the per-barrier LDS read floods of independent blocks
// interleave instead of synchronizing (R6 evidence: all pipes <=54% busy,
// lockstep barrier starvation).
// Gen: wave w produces feature-quad fq=w of each chunk for all 64 rows
// (lane l = row l), one ds_write_b64/thread/chunk.
// ---------------------------------------------------------------------------
template<int CH, int FQ>
__device__ __forceinline__ void genQuadW(const float (&x)[DIM], uint2* sA2, int l) {
    constexpr int P = CH * 32 + FQ * 4;
    const float v0 = genOne<P, 0>(x), v1 = genOne<P, 1>(x);
    const float v2 = genOne<P, 2>(x), v3 = genOne<P, 3>(x);
    constexpr int S  = FQ >> 2;          // k16-step within chunk
    constexpr int KG = (FQ >> 1) & 1;    // k-group (8-slice)
    constexpr int HI = FQ & 1;           // which 4 bf16 of the lane's 8
    uint2 u;
    u.x = pkbf(v0, v1);
    u.y = pkbf(v2, v3);
    // buffer (CH&1), granule S*2 + rowblk(l>>5), slot KG*32 + (l&31), half HI
    sA2[(((CH & 1) * 4 + S * 2 + (l >> 5)) * 64 + KG * 32 + (l & 31)) * 2 + HI] = u;
}

template<int CH>
__device__ __forceinline__ void genChunk(const float (&x)[DIM], uint2* sA2,
                                         int w, int l) {
    if constexpr (CH < 17) {
        if      (w == 0) genQuadW<CH, 0>(x, sA2, l);
        else if (w == 1) genQuadW<CH, 1>(x, sA2, l);
        else if (w == 2) genQuadW<CH, 2>(x, sA2, l);
        else if (w == 3) genQuadW<CH, 3>(x, sA2, l);
        else if (w == 4) genQuadW<CH, 4>(x, sA2, l);
        else if (w == 5) genQuadW<CH, 5>(x, sA2, l);
        else if (w == 6) genQuadW<CH, 6>(x, sA2, l);
        else             genQuadW<CH, 7>(x, sA2, l);
    } else {                             // chunk 17: 16 features = 4 quads
        if      (w == 0) genQuadW<CH, 0>(x, sA2, l);
        else if (w == 1) genQuadW<CH, 1>(x, sA2, l);
        else if (w == 2) genQuadW<CH, 2>(x, sA2, l);
        else if (w == 3) genQuadW<CH, 3>(x, sA2, l);
    }
}

template<int C>
__device__ __forceinline__ void doChunk(const float (&x)[DIM],
    uint4* sA4, uint4* sB4, const uint4* __restrict__ PsiF4,
    f32x16 (&acc)[2], int l, int w, int rb, int cq)
{
    // entry (prev barrier): DMA(C) landed in sB[C&1]; gen(C) in sA[C&1];
    // sB[(C+1)&1] free (body C-1 readers sealed by its barrier).

    // issue DMA(C+1); drained by this body's end barrier (full-body cover)
    if constexpr (C + 1 < NCH) {
        constexpr int NI = (C + 1 == 17) ? 1 : 2;   // chunk 17 = 512 granules
        const uint4* src = PsiF4 + (C + 1) * 1024 + w * 64 + l;
        uint4* dst = sB4 + ((C + 1) & 1) * 1024 + w * 64 + l;
#pragma unroll
        for (int i = 0; i < NI; ++i) dma16(src + i * 512, dst + i * 512);
    }

    // gen next chunk's A into the other sA buffer (VALU; overlaps MFMA)
    if constexpr (C + 1 < NCH) genChunk<C + 1>(x, (uint2*)sA4, w, l);

    // MFMA: wave tile 32r x 64c
    constexpr int NS = (C < 17) ? 2 : 1;            // K16-steps in this chunk
    const uint4* aa = sA4 + (C & 1) * 256;
    const uint4* bb = sB4 + (C & 1) * 1024;
#pragma unroll
    for (int s = 0; s < NS; ++s) {
        short8 a = __builtin_bit_cast(short8, aa[(s * 2 + rb) * 64 + l]);
#pragma unroll
        for (int j = 0; j < 2; ++j) {
            short8 b = __builtin_bit_cast(short8, bb[(s * 8 + cq * 2 + j) * 64 + l]);
            acc[j] = __builtin_amdgcn_mfma_f32_32x32x16_bf16(a, b, acc[j], 0, 0, 0);
        }
    }

    __syncthreads();   // publish gen(C+1), drain DMA(C+1), seal sB[C&1] reads
}

__global__ __launch_bounds__(512, 6) void gmm_mfma(
    const float* __restrict__ points,
    const unsigned short* __restrict__ PsiF,
    const float* __restrict__ kc2,
    const float* __restrict__ thr,
    float* __restrict__ out)
{
    __shared__ uint4 sA4[512];           // 8 KB: A double buffer (2 x 4 KB)
    __shared__ uint4 sB4[2048];          // 32 KB: B double buffer (2 x 16 KB)
    // epilogue scratch overlaid on sA4 buffer 0 (chunk 17 reads buffer 1 +
    // sB -- disjoint): sM [64][4] 1 KB, sS [64][4] 1 KB
    float (*sM)[4] = (float (*)[4])sA4;
    float (*sS)[4] = (float (*)[4])(sA4 + 64);

    const int t = threadIdx.x;
    const int w = t >> 6, l = t & 63;
    const int rb = w >> 2, cq = w & 3;   // mfma wave tile: 32r x 64c

    const uint4* PsiF4 = (const uint4*)PsiF;

    // prologue DMA: chunk 0 -> sB[0]
    {
        const uint4* src = PsiF4 + w * 64 + l;
        uint4* dst = sB4 + w * 64 + l;
        dma16(src,       dst);
        dma16(src + 512, dst + 512);
    }

    // x of row l (gen role: every wave covers all 64 rows, lane l = row l;
    // 8 threads/row hit the same cache lines -> L1-served redundancy)
    float x[DIM];
    const float4* px = (const float4*)(points + ((size_t)blockIdx.x * 64 + l) * DIM);
#pragma unroll
    for (int j2 = 0; j2 < 8; ++j2) {
        float4 v = px[j2];
        x[4 * j2 + 0] = v.x; x[4 * j2 + 1] = v.y;
        x[4 * j2 + 2] = v.z; x[4 * j2 + 3] = v.w;
    }

    f32x16 acc[2];
#pragma unroll
    for (int j = 0; j < 2; ++j)
#pragma unroll
        for (int r = 0; r < 16; ++r) acc[j][r] = 0.f;

    genChunk<0>(x, (uint2*)sA4, w, l);
    __syncthreads();   // one-time full drain: DMA(0) landed, gen(0) published

    doChunk<0>(x, sA4, sB4, PsiF4, acc, l, w, rb, cq);
    doChunk<1>(x, sA4, sB4, PsiF4, acc, l, w, rb, cq);
    doChunk<2>(x, sA4, sB4, PsiF4, acc, l, w, rb, cq);
    doChunk<3>(x, sA4, sB4, PsiF4, acc, l, w, rb, cq);
    doChunk<4>(x, sA4, sB4, PsiF4, acc, l, w, rb, cq);
    doChunk<5>(x, sA4, sB4, PsiF4, acc, l, w, rb, cq);
    doChunk<6>(x, sA4, sB4, PsiF4, acc, l, w, rb, cq);
    doChunk<7>(x, sA4, sB4, PsiF4, acc, l, w, rb, cq);
    doChunk<8>(x, sA4, sB4, PsiF4, acc, l, w, rb, cq);
    doChunk<9>(x, sA4, sB4, PsiF4, acc, l, w, rb, cq);
    doChunk<10>(x, sA4, sB4, PsiF4, acc, l, w, rb, cq);
    doChunk<11>(x, sA4, sB4, PsiF4, acc, l, w, rb, cq);
    doChunk<12>(x, sA4, sB4, PsiF4, acc, l, w, rb, cq);
    doChunk<13>(x, sA4, sB4, PsiF4, acc, l, w, rb, cq);
    doChunk<14>(x, sA4, sB4, PsiF4, acc, l, w, rb, cq);
    doChunk<15>(x, sA4, sB4, PsiF4, acc, l, w, rb, cq);
    doChunk<16>(x, sA4, sB4, PsiF4, acc, l, w, rb, cq);
    doChunk<17>(x, sA4, sB4, PsiF4, acc, l, w, rb, cq);

    // epilogue: add kc2, row-wise LSE over 256 cols (four 64-col quarters)
    const float kcv0 = kc2[(cq * 2 + 0) * 32 + (l & 31)];
    const float kcv1 = kc2[(cq * 2 + 1) * 32 + (l & 31)];

#pragma unroll
    for (int rg = 0; rg < 16; ++rg) {
        float v0 = acc[0][rg] + kcv0;
        float v1 = acc[1][rg] + kcv1;
        float m = fmaxf(v0, v1);
#pragma unroll
        for (int mask = 1; mask < 32; mask <<= 1) m = fmaxf(m, __shfl_xor(m, mask, 64));
        float sv = __expf(v0 - m) + __expf(v1 - m);
#pragma unroll
        for (int mask = 1; mask < 32; mask <<= 1) sv += __shfl_xor(sv, mask, 64);
        if ((l & 31) == 0) {
            const int R = rb * 32 + (rg & 3) + 8 * (rg >> 2) + 4 * (l >> 5);
            sM[R][cq] = m; sS[R][cq] = sv;
        }
    }
    __syncthreads();

    if (t < 64) {
        const float m0 = sM[t][0], m1 = sM[t][1], m2 = sM[t][2], m3 = sM[t][3];
        const float M = fmaxf(fmaxf(m0, m1), fmaxf(m2, m3));
        const float Sv = sS[t][0] * __expf(m0 - M) + sS[t][1] * __expf(m1 - M)
                       + sS[t][2] * __expf(m2 - M) + sS[t][3] * __expf(m3 - M);
        out[(size_t)blockIdx.x * 64 + t] = M + __logf(Sv) - thr[0];
    }
}

extern "C" void kernel_launch(void* const* d_in, const int* in_sizes, int n_in,
                              void* d_out, int out_size, void* d_ws, size_t ws_size,
                              hipStream_t stream) {
    const float* points  = (const float*)d_in[0];
    const float* centers = (const float*)d_in[1];
    const float* covs    = (const float*)d_in[2];
    const float* weights = (const float*)d_in[3];
    const float* thr     = (const float*)d_in[4];
    float* out = (float*)d_out;

    unsigned short* PsiF = (unsigned short*)d_ws;
    float* kc2 = (float*)((char*)d_ws + PSIF_BYTES);

    gmm_pre<<<KCOMP, 256, 0, stream>>>(covs, centers, weights, PsiF, kc2);
    gmm_mfma<<<NPTS / 64, 512, 0, stream>>>(points, PsiF, kc2, thr, out);
}